// Round 3
// baseline (1369.784 us; speedup 1.0000x reference)
//
#include <hip/hip_runtime.h>

#define BT  (512*256)
#define HS  136    // h stride per batch (ushort)

using short8  = __attribute__((ext_vector_type(8))) short;
using floatx4 = __attribute__((ext_vector_type(4))) float;

__device__ inline unsigned short f2bf(float f){
  unsigned int u = __float_as_uint(f);
  u += 0x7FFFu + ((u >> 16) & 1u);          // RNE
  return (unsigned short)(u >> 16);
}
__device__ inline float fast_sig(float x){
  return __builtin_amdgcn_rcpf(1.f + __expf(-x));
}
__device__ inline float fast_tanh(float x){
  return 1.f - 2.f * __builtin_amdgcn_rcpf(1.f + __expf(2.f * x));
}

// ---------------- kernel 1: int_all + static outputs ----------------
__global__ __launch_bounds__(256) void k_int(
    const float* __restrict__ in, const float* __restrict__ w1,
    const float* __restrict__ b1, const float* __restrict__ w3,
    const float* __restrict__ b3, const float* __restrict__ scw,
    float* __restrict__ out)
{
  __shared__ floatx4 lw[128];
  __shared__ float   l3[128];
  int tid = threadIdx.x;
  if(tid < 128){
    floatx4 v = { w1[tid*3+0], w1[tid*3+1], w1[tid*3+2], b1[tid] };
    lw[tid] = v; l3[tid] = w3[tid];
  }
  __syncthreads();
  int idx = blockIdx.x*256 + tid;
  int b = idx >> 8, t = idx & 255;
  const float* row = in + b*1792 + t*7;
  float x0 = row[3], x1 = row[4], x2 = row[5];
  float acc = 0.f;
  #pragma unroll 8
  for(int j=0;j<128;j++){
    floatx4 w = lw[j];
    float r = fmaxf(w.x*x0 + w.y*x1 + w.z*x2 + w.w, 0.f);
    acc += r * l3[j];
  }
  float v = fast_sig(acc + b3[0]) * scw[0];
  out[idx + BT]   = row[6];                  // HVAC_list
  out[idx + 3*BT] = (t < 8) ? 0.f : v;       // Int_list (also read by k_seq)
  if(t < 8){
    out[idx]        = row[0];                // TOut[:, :8] = T0
    out[idx + 2*BT] = 0.f;                   // Ext_list[:, :8] = 0
  }
}

// ---------------- kernel 2: persistent sequential recurrence ----------------
// 512 threads = 8 waves (2/SIMD). Wave wv owns hidden units u = 16wv+l15; its 4
// N-tiles are the 4 gate rows {u,128+u,256+u,384+u}. Batch0 h sits in A-row 0,
// batch1 h in A-row 4, so D-row0 -> quad0 reg0 and D-row4 -> quad1 reg0: every
// update lane has all 4 gates of its (batch,unit) in reg0 -- NO shuffles.
__global__ __launch_bounds__(512,2) void k_seq(
    const float* __restrict__ in,
    const float* __restrict__ Wih,  const float* __restrict__ Whh,
    const float* __restrict__ bih,  const float* __restrict__ bhh,
    const float* __restrict__ fc1w, const float* __restrict__ fc1b,
    const float* __restrict__ fc2w, const float* __restrict__ fc2b,
    const float* __restrict__ zonew,
    float* __restrict__ out)
{
  __shared__ __align__(16) unsigned short h_lds[2][2*HS];   // [buf][batch*HS + unit]
  __shared__ __align__(16) unsigned short emb[16*8];        // rows m=b*8+k, cols 0..4
  __shared__ __align__(16) unsigned short zpad[8];
  __shared__ float xg[8192];        // [k][b][512 gate rows], biases folded in
  __shared__ float obuf[256];       // fc1 relu out, [b][128]
  __shared__ float toutl[512];      // TOut history, [b][256]
  __shared__ float inl[3584];       // staged input rows, [b][256][7]
  __shared__ float itl[512];        // staged int_all, [b][256]
  __shared__ float E_l[2], hvit[2], t0i[2];

  const int tid  = threadIdx.x;
  const int wv   = tid >> 6;            // 0..7
  const int ln   = tid & 63;
  const int l15  = ln & 15;
  const int quad = ln >> 4;
  const int bb   = blockIdx.x;          // batches 2*bb, 2*bb+1

  // ---- stage inputs + init LDS ----
  for(int p = tid; p < 3584; p += 512) inl[p] = in[bb*3584 + p];
  itl[tid] = out[3*BT + bb*512 + tid];
  for(int p = tid; p < 16*8; p += 512) emb[p] = 0;
  if(tid < 8) zpad[tid] = 0;
  if(tid < 256) h_lds[0][(tid>>7)*HS + (tid&127)] = 0x3F80;   // h = 1.0
  if(tid < 16) toutl[(tid>>3)*256 + (tid&7)] = in[(2*bb+(tid>>3))*1792 + (tid&7)*7];
  if(tid < 2)  E_l[tid] = in[(2*bb+tid)*1792 + 56];           // E = T0[:,8]

  // ---- weight fragments into VGPRs ----
  short8 wfr[4][4];     // [gate g][K-chunk q], n = 128g + 16wv + l15
  short8 xfr[4];        // W_ih, K=32 pad (5 valid)
  short8 ffr[4];        // fc1, n = 16wv + l15
  float  bsum[4];
  #pragma unroll
  for(int g=0; g<4; g++){
    int n = 128*g + 16*wv + l15;
    bsum[g] = bih[n] + bhh[n];
    #pragma unroll
    for(int q=0; q<4; q++){
      short8 f;
      #pragma unroll
      for(int j=0;j<8;j++) f[j] = (short)f2bf(Whh[n*128 + q*32 + quad*8 + j]);
      wfr[g][q] = f;
    }
    short8 f;
    #pragma unroll
    for(int j=0;j<8;j++){ int kk = quad*8 + j; f[j] = (short)f2bf(kk < 5 ? Wih[n*5 + kk] : 0.f); }
    xfr[g] = f;
  }
  {
    int n = 16*wv + l15;
    #pragma unroll
    for(int q=0; q<4; q++){
      short8 f;
      #pragma unroll
      for(int j=0;j<8;j++) f[j] = (short)f2bf(fc1w[n*128 + q*32 + quad*8 + j]);
      ffr[q] = f;
    }
  }

  const float fb    = fc1b[16*wv + l15];
  const float fw0   = fc2w[ln];
  const float fw1   = fc2w[64 + ln];
  const float fc2b0 = fc2b[0];
  const float zw    = zonew[0];
  const int   u     = 16*wv + l15;          // this lane's hidden unit
  const bool  hload = (l15 == 0) || (l15 == 4);
  const int   hbase = (l15 >> 2)*HS + quad*8;  // A-row 0 -> batch0, A-row 4 -> batch1
  float c0 = 1.f;                           // cell state (quad<2 lanes)
  __syncthreads();

  #pragma unroll 1
  for(int i=8; i<256; i++){
    // -------- phase A: TOut[:,i]=E, build embed window, scalars --------
    if(tid < 16){
      int m = tid>>3, kk = tid&7;           // batch m, window pos kk
      int p = i - 7 + kk;
      const float* rp = inl + m*1792 + p*7;
      float tos = (p == i) ? E_l[m] : toutl[m*256 + p];
      float tmix;
      if(i < 128){
        float ratio = (float)i * 0.0078125f;
        tmix = rp[0]*ratio + tos*(1.f - ratio);
      } else tmix = tos;
      int e = (m*8 + kk)*8;                 // A row = b*8+k
      emb[e+0]=f2bf(tmix); emb[e+1]=f2bf(rp[1]); emb[e+2]=f2bf(rp[2]);
      emb[e+3]=f2bf(rp[3]); emb[e+4]=f2bf(rp[4]);
    }
    if(tid < 2){
      float Ev = E_l[tid];
      toutl[tid*256 + i] = Ev;
      out[(2*bb+tid)*256 + i] = Ev;                                   // TOut
      hvit[tid] = inl[tid*1792 + i*7 + 6] + itl[tid*256 + i];
      t0i[tid]  = inl[tid*1792 + i*7];
    }
    __syncthreads();

    // -------- x @ W_ih.T for all 8 inner steps in one MFMA set --------
    {
      short8 ea = (quad == 0) ? *(const short8*)&emb[l15*8]
                              : *(const short8*)&zpad[0];
      #pragma unroll
      for(int g=0; g<4; g++){
        floatx4 z = {0.f,0.f,0.f,0.f};
        floatx4 xa = __builtin_amdgcn_mfma_f32_16x16x32_bf16(ea, xfr[g], z, 0,0,0);
        #pragma unroll
        for(int r=0; r<4; r++){
          int mm = quad*4 + r;              // D row = b*8+k
          xg[((mm & 7)*2 + (mm >> 3))*512 + 128*g + u] = xa[r] + bsum[g];
        }
      }
    }
    __syncthreads();

    // -------- preload all 8 steps' x-gate values into VGPRs --------
    float xv[8][4];
    if(ln < 32){
      #pragma unroll
      for(int k=0;k<8;k++){
        #pragma unroll
        for(int g=0;g<4;g++) xv[k][g] = xg[(k*2 + quad)*512 + 128*g + u];
      }
    }

    // -------- 8 inner LSTM steps, ONE barrier each, NO shuffles --------
    #pragma unroll
    for(int k=0; k<8; k++){
      const unsigned short* hb = h_lds[k & 1];
      short8 a0, a1, a2, a3;
      if(hload){
        const unsigned short* hp = hb + hbase;
        a0 = *(const short8*)(hp);
        a1 = *(const short8*)(hp + 32);
        a2 = *(const short8*)(hp + 64);
        a3 = *(const short8*)(hp + 96);
      } else {
        short8 z8 = 0;
        a0 = z8; a1 = z8; a2 = z8; a3 = z8;
      }
      floatx4 acc[4];
      #pragma unroll
      for(int g=0; g<4; g++){
        floatx4 z = {0.f,0.f,0.f,0.f};
        z = __builtin_amdgcn_mfma_f32_16x16x32_bf16(a0, wfr[g][0], z, 0,0,0);
        z = __builtin_amdgcn_mfma_f32_16x16x32_bf16(a1, wfr[g][1], z, 0,0,0);
        z = __builtin_amdgcn_mfma_f32_16x16x32_bf16(a2, wfr[g][2], z, 0,0,0);
        z = __builtin_amdgcn_mfma_f32_16x16x32_bf16(a3, wfr[g][3], z, 0,0,0);
        acc[g] = z;
      }
      if(ln < 32){                          // quad = batch
        float gi = acc[0][0] + xv[k][0];
        float gf = acc[1][0] + xv[k][1];
        float gg = acc[2][0] + xv[k][2];
        float go = acc[3][0] + xv[k][3];
        c0 = fast_sig(gf)*c0 + fast_sig(gi)*fast_tanh(gg);
        float hh = fast_sig(go)*fast_tanh(c0);
        h_lds[(k+1) & 1][quad*HS + u] = f2bf(hh);
      }
      __syncthreads();
    }

    // -------- fc1 (h in buf 0 after k=7) --------
    {
      const unsigned short* hb = h_lds[0];
      short8 a0, a1, a2, a3;
      if(hload){
        const unsigned short* hp = hb + hbase;
        a0 = *(const short8*)(hp);
        a1 = *(const short8*)(hp + 32);
        a2 = *(const short8*)(hp + 64);
        a3 = *(const short8*)(hp + 96);
      } else {
        short8 z8 = 0;
        a0 = z8; a1 = z8; a2 = z8; a3 = z8;
      }
      floatx4 fa = {0.f,0.f,0.f,0.f};
      fa = __builtin_amdgcn_mfma_f32_16x16x32_bf16(a0, ffr[0], fa, 0,0,0);
      fa = __builtin_amdgcn_mfma_f32_16x16x32_bf16(a1, ffr[1], fa, 0,0,0);
      fa = __builtin_amdgcn_mfma_f32_16x16x32_bf16(a2, ffr[2], fa, 0,0,0);
      fa = __builtin_amdgcn_mfma_f32_16x16x32_bf16(a3, ffr[3], fa, 0,0,0);
      if(ln < 32){                          // D row0/row4 -> quad0/quad1 reg0
        obuf[quad*128 + u] = fmaxf(fa[0] + fb, 0.f);
      }
    }
    __syncthreads();

    // -------- fc2 + E update (waves 0,1 = batch 0,1) --------
    if(wv < 2){
      float v = obuf[wv*128 + ln]*fw0 + obuf[wv*128 + 64 + ln]*fw1;
      #pragma unroll
      for(int off=32; off; off >>= 1) v += __shfl_xor(v, off, 64);
      if(ln == 0){
        float ext   = v + fc2b0;
        float total = ext + hvit[wv];
        float E = E_l[wv];
        if(i < 128){
          float ratio = (float)i * 0.0078125f;
          E = ratio*t0i[wv] + (1.f - ratio)*E + total*zw;
        } else {
          E = E + total*zw;
        }
        E_l[wv] = E;
        out[2*BT + (2*bb+wv)*256 + i] = ext;                          // Ext_list
      }
    }
    __syncthreads();
  }
}

extern "C" void kernel_launch(void* const* d_in, const int* in_sizes, int n_in,
                              void* d_out, int out_size, void* d_ws, size_t ws_size,
                              hipStream_t stream)
{
  const float* in   = (const float*)d_in[0];
  const float* Wih  = (const float*)d_in[1];
  const float* Whh  = (const float*)d_in[2];
  const float* bih  = (const float*)d_in[3];
  const float* bhh  = (const float*)d_in[4];
  const float* fc1w = (const float*)d_in[5];
  const float* fc1b = (const float*)d_in[6];
  const float* fc2w = (const float*)d_in[7];
  const float* fc2b = (const float*)d_in[8];
  const float* i1w  = (const float*)d_in[9];
  const float* i1b  = (const float*)d_in[10];
  const float* i3w  = (const float*)d_in[11];
  const float* i3b  = (const float*)d_in[12];
  const float* scw  = (const float*)d_in[13];
  const float* zw   = (const float*)d_in[14];
  float* out = (float*)d_out;

  k_int<<<dim3(512), dim3(256), 0, stream>>>(in, i1w, i1b, i3w, i3b, scw, out);
  k_seq<<<dim3(256), dim3(512), 0, stream>>>(in, Wih, Whh, bih, bhh,
                                             fc1w, fc1b, fc2w, fc2b, zw, out);
}

// Round 4
// 1184.008 us; speedup vs baseline: 1.1569x; 1.1569x over previous
//
#include <hip/hip_runtime.h>

#define BT   (512*256)
#define HS   136      // per-batch h stride (shorts), 272 B, 16B-aligned
#define HZ   272      // zero-region offset inside each h buffer (shorts)
#define HBUF 400      // h buffer stride (shorts) = 2*HS + 128 zeros

using short8  = __attribute__((ext_vector_type(8))) short;
using floatx4 = __attribute__((ext_vector_type(4))) float;

__device__ inline unsigned short f2bf(float f){
  unsigned int u = __float_as_uint(f);
  u += 0x7FFFu + ((u >> 16) & 1u);          // RNE
  return (unsigned short)(u >> 16);
}
__device__ inline float rcpf(float x){ return __builtin_amdgcn_rcpf(x); }

// One persistent kernel: 256 blocks x 256 threads (4 waves = 1 wave/SIMD).
// Wave wv owns units 32wv..32wv+31. Tiles (g,hh): gate rows n=128g+32wv+16hh+l15.
// A rows {0,4,8,12} = {b0,b1,b0-dup,b1-dup} -> lane(quad,l15): batch=quad&1,
// unit=32wv+16*(quad>>1)+l15, gates natively in reg0 of acc[g][quad>>1].
__global__ __launch_bounds__(256,1) void k_seq(
    const float* __restrict__ in,
    const float* __restrict__ Wih,  const float* __restrict__ Whh,
    const float* __restrict__ bih,  const float* __restrict__ bhh,
    const float* __restrict__ fc1w, const float* __restrict__ fc1b,
    const float* __restrict__ fc2w, const float* __restrict__ fc2b,
    const float* __restrict__ i1w,  const float* __restrict__ i1b,
    const float* __restrict__ i3w,  const float* __restrict__ i3b,
    const float* __restrict__ scw,  const float* __restrict__ zonew,
    float* __restrict__ out)
{
  __shared__ __align__(16) unsigned short hbuf[2][HBUF]; // [buf]{b0 h, b1 h, 128 zeros}
  __shared__ __align__(16) unsigned short emb[128];      // 16 rows x 8 (cols 5..7 = 0)
  __shared__ float xg[8192];       // [k][b][512 gates], biases folded in
  __shared__ float obuf[256];      // fc1 relu out [b][128]
  __shared__ float toutl[512];     // TOut history [b][256]
  __shared__ float inl[3584];      // staged input rows [b][256][7]
  __shared__ float itl[512];       // int_all [b][256]
  __shared__ float E_l[2], hvit[2], t0i[2];

  const int tid=threadIdx.x, wv=tid>>6, ln=tid&63, l15=ln&15, quad=ln>>4;
  const int bb=blockIdx.x;

  // ---- stage inputs, zero LDS ----
  for(int p=tid;p<3584;p+=256) inl[p]=in[bb*3584+p];
  for(int p=tid;p<2*HBUF;p+=256) ((unsigned short*)hbuf)[p]=0;
  if(tid<128) emb[tid]=0;
  __syncthreads();
  hbuf[0][(tid>>7)*HS + (tid&127)] = 0x3F80;            // h = 1.0
  if(tid<16) toutl[(tid>>3)*256+(tid&7)] = inl[(tid>>3)*1792+(tid&7)*7];
  if(tid<2)  E_l[tid] = inl[tid*1792+56];               // E = T0[:,8]

  // ---- fused int module (was k_int) ----
  {
    float* lw4 = xg;            // 128 x {w0,w1,w2,b}
    float* l3  = xg + 512;
    if(tid<128){
      lw4[tid*4+0]=i1w[tid*3+0]; lw4[tid*4+1]=i1w[tid*3+1];
      lw4[tid*4+2]=i1w[tid*3+2]; lw4[tid*4+3]=i1b[tid];
      l3[tid]=i3w[tid];
    }
    __syncthreads();
    const float b30=i3b[0], sc0=scw[0];
    #pragma unroll
    for(int rep=0;rep<2;rep++){
      int idx=tid+256*rep, b=idx>>8, t=idx&255;
      const float* row = inl + b*1792 + t*7;
      float x0=row[3],x1=row[4],x2=row[5], acc=0.f;
      #pragma unroll 8
      for(int j=0;j<128;j++){
        float r=fmaxf(lw4[j*4]*x0+lw4[j*4+1]*x1+lw4[j*4+2]*x2+lw4[j*4+3],0.f);
        acc += r*l3[j];
      }
      float v = rcpf(1.f+__expf(-(acc+b30)))*sc0;
      float itv = (t<8)?0.f:v;
      int gb = 2*bb+b;
      itl[b*256+t]=itv;
      out[3*BT+gb*256+t]=itv;            // Int_list
      out[BT+gb*256+t]=row[6];           // HVAC_list
      if(t<8){ out[gb*256+t]=row[0]; out[2*BT+gb*256+t]=0.f; }
    }
  }

  // ---- weight fragments into VGPRs ----
  short8 wfr[4][2][4];   // [g][hh][Kchunk]
  short8 xfr[4][2];
  short8 ffr[2][4];
  float  bsum[4][2];
  #pragma unroll
  for(int g=0;g<4;g++){
    #pragma unroll
    for(int hh=0;hh<2;hh++){
      int n = 128*g + 32*wv + 16*hh + l15;
      bsum[g][hh] = bih[n]+bhh[n];
      #pragma unroll
      for(int Q=0;Q<4;Q++){
        short8 f;
        #pragma unroll
        for(int j=0;j<8;j++) f[j]=(short)f2bf(Whh[n*128 + Q*32 + quad*8 + j]);
        wfr[g][hh][Q]=f;
      }
      short8 f;
      #pragma unroll
      for(int j=0;j<8;j++){ int kk=quad*8+j; f[j]=(short)f2bf(kk<5?Wih[n*5+kk]:0.f); }
      xfr[g][hh]=f;
    }
  }
  #pragma unroll
  for(int hh=0;hh<2;hh++){
    int n = 32*wv + 16*hh + l15;
    #pragma unroll
    for(int Q=0;Q<4;Q++){
      short8 f;
      #pragma unroll
      for(int j=0;j<8;j++) f[j]=(short)f2bf(fc1w[n*128 + Q*32 + quad*8 + j]);
      ffr[hh][Q]=f;
    }
  }

  // ---- per-lane persistent scalars ----
  const int  u     = 32*wv + 16*(quad>>1) + l15;  // this lane's unit
  const int  bm    = quad & 1;                    // this lane's batch
  const bool hi2   = quad >= 2;
  const int  aoff  = ((l15&3)==0) ? ((l15>>2)&1)*HS + quad*8 : HZ + quad*8;
  const int  xbase = bm*512 + u;
  const int  hwoff = bm*HS + u;
  const float fb    = fc1b[u];
  const float fw0   = fc2w[ln];
  const float fw1   = fc2w[64+ln];
  const float fc2b0 = fc2b[0];
  const float zw    = zonew[0];
  float c0 = 1.f;
  __syncthreads();

  #pragma unroll 1
  for(int i=8;i<256;i++){
    // -------- phase A: TOut[:,i]=E, embed window, scalars --------
    if(tid<16){
      int m=tid>>3, kk=tid&7, p=i-7+kk;
      const float* rp = inl + m*1792 + p*7;
      float tos = (p==i) ? E_l[m] : toutl[m*256+p];
      float tmix;
      if(i<128){
        float ratio=(float)i*0.0078125f;
        tmix = rp[0]*ratio + tos*(1.f-ratio);
      } else tmix = tos;
      int e=(m*8+kk)*8;
      emb[e+0]=f2bf(tmix); emb[e+1]=f2bf(rp[1]); emb[e+2]=f2bf(rp[2]);
      emb[e+3]=f2bf(rp[3]); emb[e+4]=f2bf(rp[4]);
    }
    if(tid<2){
      float Ev=E_l[tid];
      toutl[tid*256+i]=Ev;
      out[(2*bb+tid)*256+i]=Ev;                              // TOut
      hvit[tid]=inl[tid*1792+i*7+6]+itl[tid*256+i];
      t0i[tid]=inl[tid*1792+i*7];
    }
    __syncthreads();

    // -------- x @ W_ih.T for 8 inner steps (8 MFMAs/wave) --------
    {
      const unsigned short* ep = (quad==0) ? (emb + l15*8) : (hbuf[0]+HZ+quad*8);
      short8 ea = *(const short8*)ep;
      #pragma unroll
      for(int g=0;g<4;g++){
        #pragma unroll
        for(int hh=0;hh<2;hh++){
          floatx4 z={0.f,0.f,0.f,0.f};
          z=__builtin_amdgcn_mfma_f32_16x16x32_bf16(ea, xfr[g][hh], z,0,0,0);
          #pragma unroll
          for(int r=0;r<4;r++){
            int m=4*quad+r;                 // m = b*8+k
            xg[(m&7)*1024 + (m>>3)*512 + 128*g + 32*wv+16*hh+l15] = z[r]+bsum[g][hh];
          }
        }
      }
    }
    __syncthreads();

    // -------- 8 inner LSTM steps, 1 barrier each, branch-free --------
    #pragma unroll
    for(int k=0;k<8;k++){
      const unsigned short* ab = hbuf[k&1] + aoff;
      short8 a0=*(const short8*)(ab);
      short8 a1=*(const short8*)(ab+32);
      short8 a2=*(const short8*)(ab+64);
      short8 a3=*(const short8*)(ab+96);
      float xv0=xg[k*1024+xbase      ];
      float xv1=xg[k*1024+xbase+128 ];
      float xv2=xg[k*1024+xbase+256 ];
      float xv3=xg[k*1024+xbase+384 ];
      floatx4 acc[4][2];
      #pragma unroll
      for(int g=0;g<4;g++){
        #pragma unroll
        for(int hh=0;hh<2;hh++){
          floatx4 z={0.f,0.f,0.f,0.f};
          z=__builtin_amdgcn_mfma_f32_16x16x32_bf16(a0,wfr[g][hh][0],z,0,0,0);
          z=__builtin_amdgcn_mfma_f32_16x16x32_bf16(a1,wfr[g][hh][1],z,0,0,0);
          z=__builtin_amdgcn_mfma_f32_16x16x32_bf16(a2,wfr[g][hh][2],z,0,0,0);
          z=__builtin_amdgcn_mfma_f32_16x16x32_bf16(a3,wfr[g][hh][3],z,0,0,0);
          acc[g][hh]=z;
        }
      }
      float gi=(hi2?acc[0][1][0]:acc[0][0][0])+xv0;
      float gf=(hi2?acc[1][1][0]:acc[1][0][0])+xv1;
      float gg=(hi2?acc[2][1][0]:acc[2][0][0])+xv2;
      float go=(hi2?acc[3][1][0]:acc[3][0][0])+xv3;
      // c = sig(gf)*c + sig(gi)*tanh(gg); h = sig(go)*tanh(c)  [merged rcp]
      float ef =__expf(-gf);
      float egi=__expf(-gi);
      float egg=__expf(-2.f*gg);
      float sf = rcpf(1.f+ef);
      float itn=(1.f-egg)*rcpf((1.f+egi)*(1.f+egg));
      c0 = sf*c0 + itn;
      float ego=__expf(-go);
      float ec =__expf(-2.f*c0);
      float hv2=(1.f-ec)*rcpf((1.f+ego)*(1.f+ec));
      hbuf[(k+1)&1][hwoff]=f2bf(hv2);
      __syncthreads();
    }

    // -------- fc1 (h in buf 0 after k=7) --------
    {
      const unsigned short* ab = hbuf[0] + aoff;
      short8 a0=*(const short8*)(ab);
      short8 a1=*(const short8*)(ab+32);
      short8 a2=*(const short8*)(ab+64);
      short8 a3=*(const short8*)(ab+96);
      floatx4 fa[2];
      #pragma unroll
      for(int hh=0;hh<2;hh++){
        floatx4 z={0.f,0.f,0.f,0.f};
        z=__builtin_amdgcn_mfma_f32_16x16x32_bf16(a0,ffr[hh][0],z,0,0,0);
        z=__builtin_amdgcn_mfma_f32_16x16x32_bf16(a1,ffr[hh][1],z,0,0,0);
        z=__builtin_amdgcn_mfma_f32_16x16x32_bf16(a2,ffr[hh][2],z,0,0,0);
        z=__builtin_amdgcn_mfma_f32_16x16x32_bf16(a3,ffr[hh][3],z,0,0,0);
        fa[hh]=z;
      }
      float fv = hi2 ? fa[1][0] : fa[0][0];
      obuf[bm*128+u]=fmaxf(fv+fb,0.f);
    }
    __syncthreads();

    // -------- fc2 + E update (waves 0,1 = batch 0,1) --------
    if(wv<2){
      float v = obuf[wv*128+ln]*fw0 + obuf[wv*128+64+ln]*fw1;
      #pragma unroll
      for(int off=32; off; off>>=1) v += __shfl_xor(v, off, 64);
      if(ln==0){
        float ext = v + fc2b0;
        float total = ext + hvit[wv];
        float E = E_l[wv];
        if(i<128){
          float ratio=(float)i*0.0078125f;
          E = ratio*t0i[wv] + (1.f-ratio)*E + total*zw;
        } else {
          E = E + total*zw;
        }
        E_l[wv]=E;
        out[2*BT+(2*bb+wv)*256+i]=ext;                       // Ext_list
      }
    }
    __syncthreads();
  }
}

extern "C" void kernel_launch(void* const* d_in, const int* in_sizes, int n_in,
                              void* d_out, int out_size, void* d_ws, size_t ws_size,
                              hipStream_t stream)
{
  const float* in   = (const float*)d_in[0];
  const float* Wih  = (const float*)d_in[1];
  const float* Whh  = (const float*)d_in[2];
  const float* bih  = (const float*)d_in[3];
  const float* bhh  = (const float*)d_in[4];
  const float* fc1w = (const float*)d_in[5];
  const float* fc1b = (const float*)d_in[6];
  const float* fc2w = (const float*)d_in[7];
  const float* fc2b = (const float*)d_in[8];
  const float* i1w  = (const float*)d_in[9];
  const float* i1b  = (const float*)d_in[10];
  const float* i3w  = (const float*)d_in[11];
  const float* i3b  = (const float*)d_in[12];
  const float* scw  = (const float*)d_in[13];
  const float* zw   = (const float*)d_in[14];
  float* out = (float*)d_out;

  k_seq<<<dim3(256), dim3(256), 0, stream>>>(in, Wih, Whh, bih, bhh,
                                             fc1w, fc1b, fc2w, fc2b,
                                             i1w, i1b, i3w, i3b, scw, zw, out);
}

// Round 5
// 1180.688 us; speedup vs baseline: 1.1602x; 1.0028x over previous
//
#include <hip/hip_runtime.h>

#define BT   (512*256)
// hbuf layout (shorts): zeros @0..127, b0 h @128..255, b1 h @288..415, len 448
// b0 dw-offset 64 (%32=0, banks 4q..), b1 dw-offset 144 (%32=16, banks 16+4q..)
// zero reads share banks with b0 at different addr -> 2-way = free (m136)
#define HB0  128
#define HB1  288
#define HLEN 448

using short8  = __attribute__((ext_vector_type(8))) short;
using floatx4 = __attribute__((ext_vector_type(4))) float;

__device__ inline unsigned short f2bf(float f){
  unsigned int u = __float_as_uint(f);
  u += 0x7FFFu + ((u >> 16) & 1u);          // RNE
  return (unsigned short)(u >> 16);
}
__device__ inline float rcpf(float x){ return __builtin_amdgcn_rcpf(x); }

// 256 blocks x 256 threads (4 waves = 1 wave/SIMD). Wave wv owns units
// 32wv..32wv+31; tiles (g,hh): gate rows n=128g+32wv+16hh+l15. A rows
// {0,4,8,12}={b0,b1,b0,b1} -> lane(quad,l15): batch=quad&1, hh=quad>>1,
// all 4 gates natively in acc[g][hh] reg0. No shuffles, no idle lanes.
__global__ __launch_bounds__(256,1) void k_seq(
    const float* __restrict__ in,
    const float* __restrict__ Wih,  const float* __restrict__ Whh,
    const float* __restrict__ bih,  const float* __restrict__ bhh,
    const float* __restrict__ fc1w, const float* __restrict__ fc1b,
    const float* __restrict__ fc2w, const float* __restrict__ fc2b,
    const float* __restrict__ i1w,  const float* __restrict__ i1b,
    const float* __restrict__ i3w,  const float* __restrict__ i3b,
    const float* __restrict__ scw,  const float* __restrict__ zonew,
    float* __restrict__ out)
{
  __shared__ __align__(16) unsigned short hbuf[2][HLEN];
  __shared__ float xg[8192];       // [k][b][512 gates], biases folded in
  __shared__ float obuf[256];      // fc1 relu out [b][128]
  __shared__ float toutl[512];     // TOut history [b][256]
  __shared__ float inl[3584];      // staged input rows [b][256][7]
  __shared__ float itl[512];       // int_all [b][256]
  __shared__ float E_l[2], hvit[2], t0i[2];

  const int tid=threadIdx.x, wv=tid>>6, ln=tid&63, l15=ln&15, quad=ln>>4;
  const int bb=blockIdx.x;

  // ---- stage inputs, zero LDS ----
  for(int p=tid;p<3584;p+=256) inl[p]=in[bb*3584+p];
  for(int p=tid;p<2*HLEN;p+=256) ((unsigned short*)hbuf)[p]=0;
  __syncthreads();
  hbuf[0][HB0 + (tid>>7)*(HB1-HB0) + (tid&127)] = 0x3F80;   // h = 1.0
  if(tid<16) toutl[(tid>>3)*256+(tid&7)] = inl[(tid>>3)*1792+(tid&7)*7];
  if(tid<2)  E_l[tid] = inl[tid*1792+56];                   // E = T0[:,8]

  // ---- fused int module ----
  {
    float* lw4 = xg;            // 128 x {w0,w1,w2,b}
    float* l3  = xg + 512;
    if(tid<128){
      lw4[tid*4+0]=i1w[tid*3+0]; lw4[tid*4+1]=i1w[tid*3+1];
      lw4[tid*4+2]=i1w[tid*3+2]; lw4[tid*4+3]=i1b[tid];
      l3[tid]=i3w[tid];
    }
    __syncthreads();
    const float b30=i3b[0], sc0=scw[0];
    #pragma unroll
    for(int rep=0;rep<2;rep++){
      int idx=tid+256*rep, b=idx>>8, t=idx&255;
      const float* row = inl + b*1792 + t*7;
      float x0=row[3],x1=row[4],x2=row[5], acc=0.f;
      #pragma unroll 8
      for(int j=0;j<128;j++){
        float r=fmaxf(lw4[j*4]*x0+lw4[j*4+1]*x1+lw4[j*4+2]*x2+lw4[j*4+3],0.f);
        acc += r*l3[j];
      }
      float v = rcpf(1.f+__expf(-(acc+b30)))*sc0;
      float itv = (t<8)?0.f:v;
      int gb = 2*bb+b;
      itl[b*256+t]=itv;
      out[3*BT+gb*256+t]=itv;            // Int_list
      out[BT+gb*256+t]=row[6];           // HVAC_list
      if(t<8){ out[gb*256+t]=row[0]; out[2*BT+gb*256+t]=0.f; }
    }
  }

  // ---- weight fragments into VGPRs ----
  short8 wfr[4][2][4];   // [g][hh][Kchunk]
  short8 xfr[4][2];
  short8 ffr[2][4];
  float  bsum[4][2];
  #pragma unroll
  for(int g=0;g<4;g++){
    #pragma unroll
    for(int hh=0;hh<2;hh++){
      int n = 128*g + 32*wv + 16*hh + l15;
      bsum[g][hh] = bih[n]+bhh[n];
      #pragma unroll
      for(int Q=0;Q<4;Q++){
        short8 f;
        #pragma unroll
        for(int j=0;j<8;j++) f[j]=(short)f2bf(Whh[n*128 + Q*32 + quad*8 + j]);
        wfr[g][hh][Q]=f;
      }
      short8 f;
      #pragma unroll
      for(int j=0;j<8;j++){ int kk=quad*8+j; f[j]=(short)f2bf(kk<5?Wih[n*5+kk]:0.f); }
      xfr[g][hh]=f;
    }
  }
  #pragma unroll
  for(int hh=0;hh<2;hh++){
    int n = 32*wv + 16*hh + l15;
    #pragma unroll
    for(int Q=0;Q<4;Q++){
      short8 f;
      #pragma unroll
      for(int j=0;j<8;j++) f[j]=(short)f2bf(fc1w[n*128 + Q*32 + quad*8 + j]);
      ffr[hh][Q]=f;
    }
  }

  // ---- per-lane persistent scalars ----
  const int  u     = 32*wv + 16*(quad>>1) + l15;
  const int  bm    = quad & 1;
  const bool hi2   = quad >= 2;
  const int  aoff  = ((l15&3)==0) ? (HB0 + ((l15>>2)&1)*(HB1-HB0) + quad*8)
                                  : (quad*8);            // zero region
  const int  xbase = bm*512 + u;
  const int  hwoff = HB0 + bm*(HB1-HB0) + u;
  const float fb    = fc1b[u];
  const float fw0   = fc2w[ln];
  const float fw1   = fc2w[64+ln];
  const float fc2b0 = fc2b[0];
  const float zw    = zonew[0];
  const floatx4 ZV  = {0.f,0.f,0.f,0.f};   // loop-invariant zero C operand
  float c0 = 1.f;
  __syncthreads();

  #pragma unroll 1
  for(int i=8;i<256;i++){
    // ===== merged phase: TOut write, embed-in-registers, x-MFMA, scalars =====
    if(tid<2){
      float Ev=E_l[tid];
      toutl[tid*256+i]=Ev;
      out[(2*bb+tid)*256+i]=Ev;                              // TOut
      hvit[tid]=inl[tid*1792+i*7+6]+itl[tid*256+i];
      t0i[tid]=inl[tid*1792+i*7];
    }
    {
      short8 ea = 0;
      if(quad==0){                        // 16 lanes build the A-frag directly
        int bE=l15>>3, kk=l15&7, p=i-7+kk;
        const float* rp = inl + bE*1792 + p*7;
        float tos = (p==i) ? E_l[bE] : toutl[bE*256+p];
        float tmix;
        if(i<128){
          float ratio=(float)i*0.0078125f;
          tmix = rp[0]*ratio + tos*(1.f-ratio);
        } else tmix = tos;
        ea[0]=(short)f2bf(tmix); ea[1]=(short)f2bf(rp[1]);
        ea[2]=(short)f2bf(rp[2]); ea[3]=(short)f2bf(rp[3]);
        ea[4]=(short)f2bf(rp[4]);
      }
      #pragma unroll
      for(int g=0;g<4;g++){
        #pragma unroll
        for(int hh=0;hh<2;hh++){
          floatx4 z=__builtin_amdgcn_mfma_f32_16x16x32_bf16(ea, xfr[g][hh], ZV,0,0,0);
          #pragma unroll
          for(int r=0;r<4;r++){
            int m=4*quad+r;               // m = b*8+k
            xg[(m&7)*1024 + (m>>3)*512 + 128*g + 32*wv+16*hh+l15] = z[r]+bsum[g][hh];
          }
        }
      }
    }
    __syncthreads();

    // ===== 8 inner LSTM steps, 1 barrier each =====
    #pragma unroll
    for(int k=0;k<8;k++){
      float xv0=xg[k*1024+xbase    ];
      float xv1=xg[k*1024+xbase+128];
      float xv2=xg[k*1024+xbase+256];
      float xv3=xg[k*1024+xbase+384];
      const unsigned short* ab = hbuf[k&1] + aoff;
      short8 a0=*(const short8*)(ab);
      short8 a1=*(const short8*)(ab+32);
      short8 a2=*(const short8*)(ab+64);
      short8 a3=*(const short8*)(ab+96);
      floatx4 acc[4][2];
      #pragma unroll
      for(int g=0;g<4;g++){
        #pragma unroll
        for(int hh=0;hh<2;hh++){
          floatx4 z=__builtin_amdgcn_mfma_f32_16x16x32_bf16(a0,wfr[g][hh][0],ZV,0,0,0);
          z=__builtin_amdgcn_mfma_f32_16x16x32_bf16(a1,wfr[g][hh][1],z,0,0,0);
          z=__builtin_amdgcn_mfma_f32_16x16x32_bf16(a2,wfr[g][hh][2],z,0,0,0);
          z=__builtin_amdgcn_mfma_f32_16x16x32_bf16(a3,wfr[g][hh][3],z,0,0,0);
          acc[g][hh]=z;
        }
      }
      float gi=(hi2?acc[0][1][0]:acc[0][0][0])+xv0;
      float gf=(hi2?acc[1][1][0]:acc[1][0][0])+xv1;
      float gg=(hi2?acc[2][1][0]:acc[2][0][0])+xv2;
      float go=(hi2?acc[3][1][0]:acc[3][0][0])+xv3;
      float ef =__expf(-gf);
      float egi=__expf(-gi);
      float egg=__expf(-2.f*gg);
      float sf = rcpf(1.f+ef);
      float itn=(1.f-egg)*rcpf((1.f+egi)*(1.f+egg));
      c0 = sf*c0 + itn;
      float ego=__expf(-go);
      float ec =__expf(-2.f*c0);
      float hv2=(1.f-ec)*rcpf((1.f+ego)*(1.f+ec));
      hbuf[(k+1)&1][hwoff]=f2bf(hv2);
      __syncthreads();
    }

    // ===== fc1 (h in buf 0 after k=7) =====
    {
      const unsigned short* ab = hbuf[0] + aoff;
      short8 a0=*(const short8*)(ab);
      short8 a1=*(const short8*)(ab+32);
      short8 a2=*(const short8*)(ab+64);
      short8 a3=*(const short8*)(ab+96);
      floatx4 fa[2];
      #pragma unroll
      for(int hh=0;hh<2;hh++){
        floatx4 z=__builtin_amdgcn_mfma_f32_16x16x32_bf16(a0,ffr[hh][0],ZV,0,0,0);
        z=__builtin_amdgcn_mfma_f32_16x16x32_bf16(a1,ffr[hh][1],z,0,0,0);
        z=__builtin_amdgcn_mfma_f32_16x16x32_bf16(a2,ffr[hh][2],z,0,0,0);
        z=__builtin_amdgcn_mfma_f32_16x16x32_bf16(a3,ffr[hh][3],z,0,0,0);
        fa[hh]=z;
      }
      float fv = hi2 ? fa[1][0] : fa[0][0];
      obuf[bm*128+u]=fmaxf(fv+fb,0.f);
    }
    __syncthreads();

    // ===== fc2 + E update (waves 0,1 = batch 0,1) =====
    if(wv<2){
      float v = obuf[wv*128+ln]*fw0 + obuf[wv*128+64+ln]*fw1;
      #pragma unroll
      for(int off=32; off; off>>=1) v += __shfl_xor(v, off, 64);
      if(ln==0){
        float ext = v + fc2b0;
        float total = ext + hvit[wv];
        float E = E_l[wv];
        if(i<128){
          float ratio=(float)i*0.0078125f;
          E = ratio*t0i[wv] + (1.f-ratio)*E + total*zw;
        } else {
          E = E + total*zw;
        }
        E_l[wv]=E;
        out[2*BT+(2*bb+wv)*256+i]=ext;                       // Ext_list
      }
    }
    __syncthreads();
  }
}

extern "C" void kernel_launch(void* const* d_in, const int* in_sizes, int n_in,
                              void* d_out, int out_size, void* d_ws, size_t ws_size,
                              hipStream_t stream)
{
  const float* in   = (const float*)d_in[0];
  const float* Wih  = (const float*)d_in[1];
  const float* Whh  = (const float*)d_in[2];
  const float* bih  = (const float*)d_in[3];
  const float* bhh  = (const float*)d_in[4];
  const float* fc1w = (const float*)d_in[5];
  const float* fc1b = (const float*)d_in[6];
  const float* fc2w = (const float*)d_in[7];
  const float* fc2b = (const float*)d_in[8];
  const float* i1w  = (const float*)d_in[9];
  const float* i1b  = (const float*)d_in[10];
  const float* i3w  = (const float*)d_in[11];
  const float* i3b  = (const float*)d_in[12];
  const float* scw  = (const float*)d_in[13];
  const float* zw   = (const float*)d_in[14];
  float* out = (float*)d_out;

  k_seq<<<dim3(256), dim3(256), 0, stream>>>(in, Wih, Whh, bih, bhh,
                                             fc1w, fc1b, fc2w, fc2b,
                                             i1w, i1b, i3w, i3b, scw, zw, out);
}